// Round 1
// 407.070 us; speedup vs baseline: 1.1577x; 1.1577x over previous
//
#include <hip/hip_runtime.h>
#include <stdint.h>

#define KTAPS 8
#define C 32
#define LDSS 33   // LDS row stride (floats): bank = (row*33+co)%32 = (row+co)%32 -> <=2-way (free, m136)

// ---------------------------------------------------------------------------
// bias_init: out[row][:] = bias, vectorized float4. Runs before the scatter
// (stream-ordered), so the fused kernel can accumulate with pure atomics.
// ---------------------------------------------------------------------------
__global__ __launch_bounds__(256) void bias_init_kernel(
    float* __restrict__ out, const float* __restrict__ bias, int n4) {
  int idx = blockIdx.x * 256 + threadIdx.x;
  if (idx >= n4) return;
  ((float4*)out)[idx] = ((const float4*)bias)[idx & 7];
}

// ---------------------------------------------------------------------------
// fused_scatter: thread-per-rule GEMM (proven shape: 8 independent float4
// gathers in flight, block-uniform k -> W on the scalar pipe, pure
// v_fmac v,s,v), then a wave-local LDS transpose so the atomic scatter is
// lane=co: one global_atomic_add_f32 instruction covers TWO complete 128B
// output rows (2 coalesced line-RMWs) instead of 64 scattered dwords.
// Total atomic line-transactions: 1.6M (vs 51.2M for the naive per-co loop).
// No __syncthreads: each wave transposes only its own 64 rules; the in-order
// LDS pipe orders the same-wave ds_write -> ds_read.
// ---------------------------------------------------------------------------
__global__ __launch_bounds__(256) void fused_scatter_kernel(
    const float* __restrict__ in, const float* __restrict__ w,
    const int* __restrict__ rules_in, const int* __restrict__ rules_out,
    float* __restrict__ out, int R) {
  __shared__ float cbuf[256 * LDSS];   // 33.8 KB
  __shared__ int   robuf[256];         // 1 KB  -> ~34.8 KB => 4 blocks/CU

  const int k     = blockIdx.y;
  const int tid   = threadIdx.x;
  const int r     = blockIdx.x * 256 + tid;
  const int lane  = tid & 63;
  const int wbase = tid & ~63;         // first rule-slot owned by this wave

  // wave-uniform early exit (safe: no barriers below, LDS use is wave-local)
  if (blockIdx.x * 256 + wbase >= R) return;

  const bool valid = (r < R);
  const int rc = valid ? r : (R - 1);
  const int ri = rules_in[(size_t)k * R + rc];
  const int ro = valid ? rules_out[(size_t)k * R + rc] : -1;
  robuf[tid] = ro;

  // 8 independent 16B gathers -- all in flight together (8KB/wave)
  const float4* rowp = (const float4*)(in + (size_t)ri * C);
  float4 av[8];
#pragma unroll
  for (int j = 0; j < 8; ++j) av[j] = rowp[j];

  float a[C];
#pragma unroll
  for (int j = 0; j < 8; ++j) {
    a[4 * j + 0] = av[j].x; a[4 * j + 1] = av[j].y;
    a[4 * j + 2] = av[j].z; a[4 * j + 3] = av[j].w;
  }

  const float* wk = w + k * (C * C);   // block-uniform -> scalar pipe
  float acc[C];
#pragma unroll
  for (int co = 0; co < C; ++co) acc[co] = a[0] * wk[co];
#pragma unroll
  for (int ci = 1; ci < C; ++ci)
#pragma unroll
    for (int co = 0; co < C; ++co)
      acc[co] = fmaf(a[ci], wk[ci * C + co], acc[co]);

  // stash this rule's 32-float contribution in LDS (stride 33 -> 2-way max)
  float* myrow = cbuf + tid * LDSS;
#pragma unroll
  for (int co = 0; co < C; ++co) myrow[co] = acc[co];

  // wave-local transpose scatter:
  //   lanes 0-31  -> rule (wbase + 2j),   lane&31 = output channel
  //   lanes 32-63 -> rule (wbase + 2j+1)
  // Each iteration: 1 ds_read_b32 (imm-offset walk, conflict-free) +
  // 1 global_atomic_add_f32 hitting exactly 2 contiguous 128B lines.
  const int co   = lane & 31;
  const int half = lane >> 5;
#pragma unroll
  for (int j = 0; j < 32; ++j) {
    const int rl  = wbase + 2 * j + half;
    const int rol = robuf[rl];                  // 2-address broadcast read
    const float v = cbuf[rl * LDSS + co];
    if (rol >= 0)
      unsafeAtomicAdd(out + (size_t)rol * C + co, v);
  }
}

extern "C" void kernel_launch(void* const* d_in, const int* in_sizes, int n_in,
                              void* d_out, int out_size, void* d_ws, size_t ws_size,
                              hipStream_t stream) {
  const float* in_features = (const float*)d_in[0];
  const float* weight      = (const float*)d_in[1];
  const float* bias        = (const float*)d_in[2];
  const int*   rules_in    = (const int*)d_in[3];
  const int*   rules_out   = (const int*)d_in[4];

  const int R = in_sizes[3] / KTAPS;   // 200000
  float* out = (float*)d_out;

  const int n_out4 = out_size / 4;     // out_size counts floats
  bias_init_kernel<<<(n_out4 + 255) / 256, 256, 0, stream>>>(out, bias, n_out4);

  dim3 grid((R + 255) / 256, KTAPS);
  fused_scatter_kernel<<<grid, 256, 0, stream>>>(in_features, weight, rules_in,
                                                 rules_out, out, R);
}